// Round 11
// baseline (157.712 us; speedup 1.0000x reference)
//
#include <hip/hip_runtime.h>
#include <hip/hip_bf16.h>

typedef __bf16 bf16x8 __attribute__((ext_vector_type(8)));
typedef __bf16 bf16x4 __attribute__((ext_vector_type(4)));
typedef float  f32x4  __attribute__((ext_vector_type(4)));
typedef float  f32x16 __attribute__((ext_vector_type(16)));

#define MFMA16(a, b, c) __builtin_amdgcn_mfma_f32_16x16x32_bf16((a), (b), (c), 0, 0, 0)
#define MFMA32(a, b, c) __builtin_amdgcn_mfma_f32_32x32x16_bf16((a), (b), (c), 0, 0, 0)

namespace {
constexpr int Bb = 2, Dd = 1024, Ss = 2048, Uu = 1024, Hh = 16;
}

#if __has_builtin(__builtin_amdgcn_exp2f)
#define EXP2(x) __builtin_amdgcn_exp2f(x)
#else
#define EXP2(x) __expf((x) * 0.6931471805599453f)
#endif

__device__ __forceinline__ uint32_t pkbf(float a, float b) {
  union { __bf16 h[2]; uint32_t u; } z;
  z.h[0] = (__bf16)a; z.h[1] = (__bf16)b;
  return z.u;
}
#define PLSWAP(a, b) asm("v_permlane32_swap_b32 %0, %1" : "+v"(a), "+v"(b))

__device__ __forceinline__ void gl16(const void* g, void* l) {
  __builtin_amdgcn_global_load_lds((const __attribute__((address_space(1))) uint32_t*)g,
                                   (__attribute__((address_space(3))) uint32_t*)l, 16, 0, 0);
}

#define VMW(n) asm volatile("s_waitcnt vmcnt(" #n ")" ::: "memory")
#define BARRIER_PIN() do { __builtin_amdgcn_s_barrier(); \
  asm volatile("" ::: "memory"); __builtin_amdgcn_sched_barrier(0); } while (0)
#define LGKM0() asm volatile("s_waitcnt lgkmcnt(0)" ::: "memory")

// ---------- transpose x: (B,D,S) f32 -> xb (B,S,D) bf16 ----------
__global__ __launch_bounds__(256) void k_xpose_x(const float* __restrict__ inp,
                                                 __bf16* __restrict__ xb) {
  __shared__ __attribute__((aligned(16))) __bf16 ts[64][72];
  const int s0 = blockIdx.x * 64, d0 = blockIdx.y * 64, b = blockIdx.z;
  const int t = threadIdx.x;
  {
    const int i = t >> 2, c = (t & 3) * 16;
    const float* src = inp + ((size_t)(b * Dd + d0 + i)) * Ss + s0 + c;
#pragma unroll
    for (int q = 0; q < 4; ++q) {
      const float4 f = *(const float4*)(src + q * 4);
      ts[i][c + q * 4 + 0] = (__bf16)f.x;
      ts[i][c + q * 4 + 1] = (__bf16)f.y;
      ts[i][c + q * 4 + 2] = (__bf16)f.z;
      ts[i][c + q * 4 + 3] = (__bf16)f.w;
    }
  }
  __syncthreads();
  {
    const int sl = t >> 2, dc = (t & 3) * 16;
    bf16x8 va, vb;
#pragma unroll
    for (int j = 0; j < 8; ++j) { va[j] = ts[dc + j][sl]; vb[j] = ts[dc + 8 + j][sl]; }
    __bf16* dst = xb + ((size_t)(b * Ss + s0 + sl)) * Dd + d0 + dc;
    *(bf16x8*)dst = va;
    *(bf16x8*)(dst + 8) = vb;
  }
}

// ---------- transpose weights: (K,N) f32 -> (N,K) bf16, 4 matrices ----------
__global__ __launch_bounds__(256) void k_xpose_w(const float* __restrict__ w0, const float* __restrict__ w1,
                                                 const float* __restrict__ w2, const float* __restrict__ w3,
                                                 __bf16* __restrict__ o0, __bf16* __restrict__ o1,
                                                 __bf16* __restrict__ o2, __bf16* __restrict__ o3) {
  __shared__ __attribute__((aligned(16))) __bf16 ts[64][72];
  const float* src_m; __bf16* dst_m;
  switch (blockIdx.z) {
    case 0: src_m = w0; dst_m = o0; break;
    case 1: src_m = w1; dst_m = o1; break;
    case 2: src_m = w2; dst_m = o2; break;
    default: src_m = w3; dst_m = o3; break;
  }
  const int n0 = blockIdx.x * 64, k0 = blockIdx.y * 64;
  const int t = threadIdx.x;
  {
    const int i = t >> 2, c = (t & 3) * 16;
    const float* src = src_m + (size_t)(k0 + i) * 1024 + n0 + c;
#pragma unroll
    for (int q = 0; q < 4; ++q) {
      const float4 f = *(const float4*)(src + q * 4);
      ts[i][c + q * 4 + 0] = (__bf16)f.x;
      ts[i][c + q * 4 + 1] = (__bf16)f.y;
      ts[i][c + q * 4 + 2] = (__bf16)f.z;
      ts[i][c + q * 4 + 3] = (__bf16)f.w;
    }
  }
  __syncthreads();
  {
    const int nl = t >> 2, kc = (t & 3) * 16;
    bf16x8 va, vb;
#pragma unroll
    for (int j = 0; j < 8; ++j) { va[j] = ts[kc + j][nl]; vb[j] = ts[kc + 8 + j][nl]; }
    __bf16* dst = dst_m + (size_t)(n0 + nl) * 1024 + k0 + kc;
    *(bf16x8*)dst = va;
    *(bf16x8*)(dst + 8) = vb;
  }
}

// ---------- 256x256-tile QKV GEMM: 4-slot LDS ring, counted vmcnt, swizzled ----------
__global__ __launch_bounds__(512, 2) void k_gemm_qkv8(const __bf16* __restrict__ A,
    const __bf16* __restrict__ W0, const __bf16* __restrict__ W1, const __bf16* __restrict__ W2,
    const float* __restrict__ b0, const float* __restrict__ b1, const float* __restrict__ b2,
    __bf16* __restrict__ Qb, __bf16* __restrict__ Kb, __bf16* __restrict__ Vt) {
  __shared__ __attribute__((aligned(16))) __bf16 As[4][256][32];
  __shared__ __attribute__((aligned(16))) __bf16 Bs[4][256][32];
  const int t = threadIdx.x;
  const int w = t >> 6, l = t & 63, lg = l >> 4, lr = l & 15;
  const int wm = w >> 2, wn = w & 3;
  const int bid = blockIdx.x;
  const int logical = (bid & 7) * 24 + (bid >> 3);
  const int z = logical >> 6;
  const int rem = logical & 63;
  const int n0 = (rem & 3) * 256, m0 = (rem >> 2) * 256;
  const __bf16* Bt = z == 0 ? W0 : z == 1 ? W1 : W2;
  const float* bias = z == 0 ? b0 : z == 1 ? b1 : b2;

  const int srow = t >> 2, sc8 = t & 3, scol = sc8 * 8;
  const int so = ((sc8 + 4 - ((srow >> 1) & 3)) & 3) * 8;
  const __bf16* gaB = A  + ((size_t)(m0 + srow)) * 1024 + so;
  const __bf16* gbB = Bt + ((size_t)(n0 + srow)) * 1024 + so;
#define STG_A(s, h, kt) gl16(gaB + (size_t)(h) * 128 * 1024 + (kt) * 32, &As[s][(h) * 128 + srow][scol])
#define STG_B(s, h, kt) gl16(gbB + (size_t)(h) * 128 * 1024 + (kt) * 32, &Bs[s][(h) * 128 + srow][scol])

  STG_A(0, 0, 0); STG_A(0, 1, 0); STG_B(0, 0, 0); STG_B(0, 1, 0);
  STG_A(1, 0, 1); STG_A(1, 1, 1); STG_B(1, 0, 1); STG_B(1, 1, 1);
  STG_A(2, 0, 2); STG_A(2, 1, 2); STG_B(2, 0, 2); STG_B(2, 1, 2);
  f32x4 acc[8][4] = {};
  VMW(8);
  BARRIER_PIN();

  const int rdc = ((lg + (lr >> 1)) & 3) * 8;
  const __bf16* Abase = &As[0][0][0] + wm * 4096 + lr * 32 + rdc;
  const __bf16* Bbase = &Bs[0][0][0] + wn * 2048 + lr * 32 + rdc;

  for (int kt = 0; kt < 32; ++kt) {
    const int sC = kt & 3, sS = (kt + 3) & 3;
    const __bf16* Ap = Abase + sC * 8192;
    const __bf16* Bp = Bbase + sC * 8192;
    bf16x8 a0, a1, a2, a3, bb0, bb1, bb2, bb3;
    a0 = *(const bf16x8*)(Ap);         a1 = *(const bf16x8*)(Ap + 512);
    a2 = *(const bf16x8*)(Ap + 1024);  a3 = *(const bf16x8*)(Ap + 1536);
    bb0 = *(const bf16x8*)(Bp);        bb1 = *(const bf16x8*)(Bp + 512);
    bb2 = *(const bf16x8*)(Bp + 1024); bb3 = *(const bf16x8*)(Bp + 1536);
    if (kt < 29) { STG_A(sS, 0, kt + 3); STG_A(sS, 1, kt + 3); }
    BARRIER_PIN();
    LGKM0(); __builtin_amdgcn_sched_barrier(0);
    __builtin_amdgcn_s_setprio(1);
    acc[0][0] = MFMA16(a0, bb0, acc[0][0]); acc[0][1] = MFMA16(a0, bb1, acc[0][1]);
    acc[0][2] = MFMA16(a0, bb2, acc[0][2]); acc[0][3] = MFMA16(a0, bb3, acc[0][3]);
    acc[1][0] = MFMA16(a1, bb0, acc[1][0]); acc[1][1] = MFMA16(a1, bb1, acc[1][1]);
    acc[1][2] = MFMA16(a1, bb2, acc[1][2]); acc[1][3] = MFMA16(a1, bb3, acc[1][3]);
    acc[2][0] = MFMA16(a2, bb0, acc[2][0]); acc[2][1] = MFMA16(a2, bb1, acc[2][1]);
    acc[2][2] = MFMA16(a2, bb2, acc[2][2]); acc[2][3] = MFMA16(a2, bb3, acc[2][3]);
    acc[3][0] = MFMA16(a3, bb0, acc[3][0]); acc[3][1] = MFMA16(a3, bb1, acc[3][1]);
    acc[3][2] = MFMA16(a3, bb2, acc[3][2]); acc[3][3] = MFMA16(a3, bb3, acc[3][3]);
    __builtin_amdgcn_s_setprio(0);
    BARRIER_PIN();
    a0 = *(const bf16x8*)(Ap + 2048);  a1 = *(const bf16x8*)(Ap + 2560);
    a2 = *(const bf16x8*)(Ap + 3072);  a3 = *(const bf16x8*)(Ap + 3584);
    if (kt < 29) { STG_B(sS, 0, kt + 3); STG_B(sS, 1, kt + 3); }
    if (kt < 29) { VMW(8); } else if (kt == 29) { VMW(4); } else if (kt == 30) { VMW(0); }
    BARRIER_PIN();
    LGKM0(); __builtin_amdgcn_sched_barrier(0);
    __builtin_amdgcn_s_setprio(1);
    acc[4][0] = MFMA16(a0, bb0, acc[4][0]); acc[4][1] = MFMA16(a0, bb1, acc[4][1]);
    acc[4][2] = MFMA16(a0, bb2, acc[4][2]); acc[4][3] = MFMA16(a0, bb3, acc[4][3]);
    acc[5][0] = MFMA16(a1, bb0, acc[5][0]); acc[5][1] = MFMA16(a1, bb1, acc[5][1]);
    acc[5][2] = MFMA16(a1, bb2, acc[5][2]); acc[5][3] = MFMA16(a1, bb3, acc[5][3]);
    acc[6][0] = MFMA16(a2, bb0, acc[6][0]); acc[6][1] = MFMA16(a2, bb1, acc[6][1]);
    acc[6][2] = MFMA16(a2, bb2, acc[6][2]); acc[6][3] = MFMA16(a2, bb3, acc[6][3]);
    acc[7][0] = MFMA16(a3, bb0, acc[7][0]); acc[7][1] = MFMA16(a3, bb1, acc[7][1]);
    acc[7][2] = MFMA16(a3, bb2, acc[7][2]); acc[7][3] = MFMA16(a3, bb3, acc[7][3]);
    __builtin_amdgcn_s_setprio(0);
    BARRIER_PIN();
  }
#undef STG_A
#undef STG_B

  const int b = m0 >> 11, sb = m0 & 2047;
  __bf16* Ct = &As[0][0][0];
  float bi[4];
#pragma unroll
  for (int j = 0; j < 4; ++j) bi[j] = bias[n0 + wn * 64 + j * 16 + lr];
  if (z < 2) {
    __bf16* out = z == 0 ? Qb : Kb;
    const float scale = z == 0 ? 0.125f * 1.44269504f : 1.0f;
    const int h0 = n0 >> 6;
    for (int c = 0; c < 4; ++c) {
      __syncthreads();
      if (wm == (c >> 1)) {
        const int q = c & 1;
#pragma unroll
        for (int j = 0; j < 4; ++j) {
          const int nl = wn * 64 + j * 16 + lr;
#pragma unroll
          for (int i2 = 0; i2 < 4; ++i2)
#pragma unroll
            for (int r = 0; r < 4; ++r)
              Ct[(i2 * 16 + lg * 4 + r) * 264 + nl] =
                  (__bf16)(fmaxf(acc[q * 4 + i2][j][r] + bi[j], 0.0f) * scale);
        }
      }
      __syncthreads();
#pragma unroll
      for (int u4 = 0; u4 < 4; ++u4) {
        const int u = u4 * 512 + t;
        const int sl = u >> 5, ru = u & 31;
        const int hh = ru >> 3, sg = ru & 7;
        const bf16x8 v = *(const bf16x8*)&Ct[sl * 264 + hh * 64 + sg * 8];
        *(bf16x8*)(out + ((size_t)(b * Hh + h0 + hh) * Ss + sb + c * 64 + sl) * 64 + sg * 8) = v;
      }
    }
  } else {
    for (int c = 0; c < 4; ++c) {
      __syncthreads();
      if (wn == c) {
#pragma unroll
        for (int j = 0; j < 4; ++j) {
          const int nli = j * 16 + lr;
#pragma unroll
          for (int mi = 0; mi < 8; ++mi)
#pragma unroll
            for (int r2 = 0; r2 < 4; r2 += 2) {
              const int ml = wm * 128 + mi * 16 + lg * 4 + r2;
              const uint32_t pk = pkbf(fmaxf(acc[mi][j][r2] + bi[j], 0.0f),
                                       fmaxf(acc[mi][j][r2 + 1] + bi[j], 0.0f));
              *(uint32_t*)&Ct[nli * 264 + ml] = pk;
            }
        }
      }
      __syncthreads();
#pragma unroll
      for (int u4 = 0; u4 < 4; ++u4) {
        const int u = u4 * 512 + t;
        const int nl = u >> 5, sg = u & 31;
        const bf16x8 v = *(const bf16x8*)&Ct[nl * 264 + sg * 8];
        *(bf16x8*)(Vt + (size_t)(b * 1024 + n0 + c * 64 + nl) * Ss + sb + sg * 8) = v;
      }
    }
  }
}

// ---------- 128x128 GEMM core (Wo): 3-buffer depth-2 counted-vmcnt ----------
__device__ __forceinline__ int swz_slot(int row, int slot) { return (slot + (row >> 1)) & 3; }

__device__ __forceinline__ void gemm_core(const __bf16* __restrict__ A, const __bf16* __restrict__ Bt,
                                          __bf16 (*__restrict__ As)[128][32], __bf16 (*__restrict__ Bs)[128][32],
                                          int m0, int n0, int t, f32x4 acc[4][4]) {
  const int w = t >> 6, l = t & 63;
  const int wm = (w >> 1) * 64, wn = (w & 1) * 64;
  const int lg = l >> 4, lr = l & 15;
  const int sr = t >> 2, sc8 = t & 3;
  const int so = ((sc8 + 4 - ((sr >> 1) & 3)) & 3) * 8;
  const __bf16* ga = A + (size_t)(m0 + sr) * 1024 + so;
  const __bf16* gb = Bt + (size_t)(n0 + sr) * 1024 + so;
  const int de = sr * 32 + sc8 * 8;
#define STG(bf, kk) { \
    gl16(ga + (kk) * 32,             &As[bf][0][0] + de); \
    gl16(ga + (kk) * 32 + 64 * 1024, &As[bf][0][0] + de + 64 * 32); \
    gl16(gb + (kk) * 32,             &Bs[bf][0][0] + de); \
    gl16(gb + (kk) * 32 + 64 * 1024, &Bs[bf][0][0] + de + 64 * 32); }
  STG(0, 0) STG(1, 1)
  for (int s = 0; s < 32; ++s) {
    if (s < 31) { VMW(4); } else { VMW(0); }
    BARRIER_PIN();
    if (s + 2 < 32) { const int b2 = (s + 2) % 3; STG(b2, s + 2) }
    const int cb = s % 3;
    bf16x8 af[4], bfr[4];
#pragma unroll
    for (int i = 0; i < 4; ++i) { const int rr = wm + i * 16 + lr; af[i]  = *(const bf16x8*)&As[cb][rr][swz_slot(rr, lg) * 8]; }
#pragma unroll
    for (int i = 0; i < 4; ++i) { const int rr = wn + i * 16 + lr; bfr[i] = *(const bf16x8*)&Bs[cb][rr][swz_slot(rr, lg) * 8]; }
#pragma unroll
    for (int i = 0; i < 4; ++i)
#pragma unroll
      for (int j = 0; j < 4; ++j) acc[i][j] = MFMA16(af[i], bfr[j], acc[i][j]);
  }
#undef STG
}

// Wo GEMM + residual(from xb bf16) + LN partial stats; Wb output bf16.
__global__ __launch_bounds__(256) void k_gemm_o(const __bf16* __restrict__ A, const __bf16* __restrict__ Bt,
                                                const float* __restrict__ bias, const __bf16* __restrict__ xb,
                                                __bf16* __restrict__ Wb, float* __restrict__ partials) {
  __shared__ __attribute__((aligned(16))) char smem[49152];
  auto As = (__bf16 (*)[128][32])smem;
  auto Bs = (__bf16 (*)[128][32])(smem + 24576);
  float* Cs = (float*)smem;  // [64][132] f32
  const int flat = blockIdx.x;
  const int logical = (flat & 7) * 32 + (flat >> 3);
  const int n0 = (logical & 7) * 128, m0 = (logical >> 3) * 128;
  const int t = threadIdx.x, w = t >> 6, l = t & 63;
  const int wm = (w >> 1) * 64, wn = (w & 1) * 64;
  const int lg = l >> 4, lr = l & 15;
  f32x4 acc[4][4] = {};
  gemm_core(A, Bt, As, Bs, m0, n0, t, acc);
  const int sub = t & 31, rid0 = t >> 5;
#pragma unroll
  for (int h2 = 0; h2 < 2; ++h2) {
    __syncthreads();
    if ((w >> 1) == h2) {
#pragma unroll
      for (int j = 0; j < 4; ++j) {
        const int nl = wn + j * 16 + lr;
        const float bi = bias[n0 + nl];
#pragma unroll
        for (int i = 0; i < 4; ++i)
#pragma unroll
          for (int r = 0; r < 4; ++r)
            Cs[(i * 16 + lg * 4 + r) * 132 + nl] = acc[i][j][r] + bi;
      }
    }
    __syncthreads();
#pragma unroll
    for (int p = 0; p < 8; ++p) {
      const int row = p * 8 + rid0;
      const int m = m0 + h2 * 64 + row;
      float4 v = *(const float4*)&Cs[row * 132 + sub * 4];
      const bf16x4 x4 = *(const bf16x4*)&xb[(size_t)m * 1024 + n0 + sub * 4];
      v.x += (float)x4[0]; v.y += (float)x4[1]; v.z += (float)x4[2]; v.w += (float)x4[3];
      bf16x4 pv;
      pv[0] = (__bf16)v.x; pv[1] = (__bf16)v.y; pv[2] = (__bf16)v.z; pv[3] = (__bf16)v.w;
      *(bf16x4*)&Wb[(size_t)m * 1024 + n0 + sub * 4] = pv;
      float s = v.x + v.y + v.z + v.w;
      float q = v.x * v.x + v.y * v.y + v.z * v.z + v.w * v.w;
      s += __shfl_xor(s, 1); s += __shfl_xor(s, 2); s += __shfl_xor(s, 4); s += __shfl_xor(s, 8);
      q += __shfl_xor(q, 1); q += __shfl_xor(q, 2); q += __shfl_xor(q, 4); q += __shfl_xor(q, 8);
      if ((sub & 15) == 0) {
        const int ci = (n0 >> 6) + (sub >> 4);
        partials[((size_t)m * 16 + ci) * 2]     = s;
        partials[((size_t)m * 16 + ci) * 2 + 1] = q;
      }
    }
  }
}

// ---------- flash attention, split-KV x2: attn6 structure, half KV range per block ----------
// Writes UNNORMALIZED O partials (bf16) + f32 row-sums l; combine kernel normalizes.
__global__ __launch_bounds__(256, 4) void k_attn9(const __bf16* __restrict__ Qg, const __bf16* __restrict__ Kg,
                                                  const __bf16* __restrict__ Vt,
                                                  __bf16* __restrict__ Op0, __bf16* __restrict__ Op1,
                                                  float* __restrict__ Lp) {
  __shared__ __attribute__((aligned(16))) char smem[36864];
  auto Ks = (__bf16 (*)[64][72])smem;
  auto Vs = (__bf16 (*)[64][72])(smem + 18432);
  __bf16* Os = (__bf16*)smem;
  const int t = threadIdx.x, l = t & 63, w = t >> 6;
  const int ln = l & 31, hi = l >> 5;
  const int bid = blockIdx.x;
  const int orig = (bid & 7) * 128 + (bid >> 3);   // 1024 = 8*128 bijective XCD-chunked
  const int bh = orig >> 5;
  const int rest = orig & 31;
  const int qt = rest >> 1, kvh = rest & 1;
  const int q0blk = qt * 128;
  const int q0w = q0blk + w * 32;
  const int b = bh >> 4, h = bh & 15;
  const size_t kbase = (size_t)bh * Ss * 64;
  const int srow = t >> 2, scol = (t & 3) * 16;
  const __bf16* Krow = Kg + kbase + (size_t)(kvh * 1024 + srow) * 64 + scol;
  const __bf16* Vrow = Vt + (size_t)(bh * 64 + srow) * Ss + kvh * 1024 + scol;

  bf16x8 qf0, qf1, qf2, qf3;
  {
    const __bf16* qp = Qg + kbase + (size_t)(q0w + ln) * 64 + hi * 8;
    qf0 = *(const bf16x8*)(qp);
    qf1 = *(const bf16x8*)(qp + 16);
    qf2 = *(const bf16x8*)(qp + 32);
    qf3 = *(const bf16x8*)(qp + 48);
  }
  f32x16 oA = {}, oB = {};
  float lrow = 0.f;

  auto tile_compute = [&](const __bf16 (&K)[64][72], const __bf16 (&V)[64][72]) {
    f32x16 s0 = {}, s1 = {};
    {
      bf16x8 kf;
#define QK(u, cc, sacc) \
      kf = *(const bf16x8*)&K[(u) * 32 + ln][(cc) * 16 + hi * 8]; \
      sacc = MFMA32(kf, qf##cc, sacc);
      QK(0, 0, s0) QK(0, 1, s0) QK(0, 2, s0) QK(0, 3, s0)
      QK(1, 0, s1) QK(1, 1, s1) QK(1, 2, s1) QK(1, 3, s1)
#undef QK
    }
#pragma unroll
    for (int r = 0; r < 16; ++r) s0[r] = EXP2(s0[r]);
#pragma unroll
    for (int r = 0; r < 16; ++r) s1[r] = EXP2(s1[r]);
    float sm[16];
#pragma unroll
    for (int r = 0; r < 8; ++r) sm[r] = s0[2 * r] + s0[2 * r + 1];
#pragma unroll
    for (int r = 0; r < 8; ++r) sm[8 + r] = s1[2 * r] + s1[2 * r + 1];
#pragma unroll
    for (int st = 8; st > 0; st >>= 1)
#pragma unroll
      for (int r = 0; r < st; ++r) sm[r] += sm[r + st];
    lrow += sm[0];
    uint32_t w0[8], w1[8];
#pragma unroll
    for (int k = 0; k < 8; ++k) w0[k] = pkbf(s0[2 * k], s0[2 * k + 1]);
#pragma unroll
    for (int k = 0; k < 8; ++k) w1[k] = pkbf(s1[2 * k], s1[2 * k + 1]);
    PLSWAP(w0[0], w0[2]); PLSWAP(w0[1], w0[3]);
    PLSWAP(w0[4], w0[6]); PLSWAP(w0[5], w0[7]);
    PLSWAP(w1[0], w1[2]); PLSWAP(w1[1], w1[3]);
    PLSWAP(w1[4], w1[6]); PLSWAP(w1[5], w1[7]);
    union U4 { uint32_t u[4]; bf16x8 v; };
    U4 z;
    bf16x8 pa0, pa1, pa2, pa3;
    z.u[0] = w0[0]; z.u[1] = w0[1]; z.u[2] = w0[2]; z.u[3] = w0[3]; pa0 = z.v;
    z.u[0] = w0[4]; z.u[1] = w0[5]; z.u[2] = w0[6]; z.u[3] = w0[7]; pa1 = z.v;
    z.u[0] = w1[0]; z.u[1] = w1[1]; z.u[2] = w1[2]; z.u[3] = w1[3]; pa2 = z.v;
    z.u[0] = w1[4]; z.u[1] = w1[5]; z.u[2] = w1[6]; z.u[3] = w1[7]; pa3 = z.v;
    {
      bf16x8 vf;
#define PV(half, ti, pa, oacc) \
      vf = *(const bf16x8*)&V[(half) * 32 + ln][(ti) * 16 + hi * 8]; \
      oacc = MFMA32(vf, pa, oacc);
      PV(0, 0, pa0, oA) PV(0, 1, pa1, oA) PV(0, 2, pa2, oA) PV(0, 3, pa3, oA)
      PV(1, 0, pa0, oB) PV(1, 1, pa1, oB) PV(1, 2, pa2, oB) PV(1, 3, pa3, oB)
#undef PV
    }
  };

  bf16x8 kA0 = *(const bf16x8*)(Krow),           kA1 = *(const bf16x8*)(Krow + 8);
  bf16x8 vA0 = *(const bf16x8*)(Vrow),           vA1 = *(const bf16x8*)(Vrow + 8);
  bf16x8 kB0 = *(const bf16x8*)(Krow + 64 * 64), kB1 = *(const bf16x8*)(Krow + 64 * 64 + 8);
  bf16x8 vB0 = *(const bf16x8*)(Vrow + 64),      vB1 = *(const bf16x8*)(Vrow + 64 + 8);

  for (int tt = 0; tt < 8; ++tt) {   // 16 local tiles (2 per iter)
    *(bf16x8*)&Ks[0][srow][scol]     = kA0;
    *(bf16x8*)&Ks[0][srow][scol + 8] = kA1;
    *(bf16x8*)&Vs[0][srow][scol]     = vA0;
    *(bf16x8*)&Vs[0][srow][scol + 8] = vA1;
    LGKM0();
    BARRIER_PIN();
    if (tt < 7) {
      const size_t ko = (size_t)(2 * tt + 2) * 64;
      kA0 = *(const bf16x8*)(Krow + ko * 64);
      kA1 = *(const bf16x8*)(Krow + ko * 64 + 8);
      vA0 = *(const bf16x8*)(Vrow + ko);
      vA1 = *(const bf16x8*)(Vrow + ko + 8);
    }
    tile_compute(Ks[0], Vs[0]);
    *(bf16x8*)&Ks[1][srow][scol]     = kB0;
    *(bf16x8*)&Ks[1][srow][scol + 8] = kB1;
    *(bf16x8*)&Vs[1][srow][scol]     = vB0;
    *(bf16x8*)&Vs[1][srow][scol + 8] = vB1;
    LGKM0();
    BARRIER_PIN();
    if (tt < 7) {
      const size_t ko = (size_t)(2 * tt + 3) * 64;
      kB0 = *(const bf16x8*)(Krow + ko * 64);
      kB1 = *(const bf16x8*)(Krow + ko * 64 + 8);
      vB0 = *(const bf16x8*)(Vrow + ko);
      vB1 = *(const bf16x8*)(Vrow + ko + 8);
    }
    tile_compute(Ks[1], Vs[1]);
  }
  // cross-half lrow sum; store per-row l (lanes hi==0 cover q0w+0..31)
  {
    uint32_t a = __builtin_bit_cast(uint32_t, lrow), bsw = a;
    PLSWAP(a, bsw);
    lrow = __builtin_bit_cast(float, a) + __builtin_bit_cast(float, bsw);
  }
  if (hi == 0)
    Lp[(size_t)kvh * 65536 + (size_t)bh * 2048 + q0w + ln] = lrow;
  // coalesced UNNORMALIZED O write via LDS re-stage
  __syncthreads();
  const int ql = w * 32 + ln;
#pragma unroll
  for (int r0 = 0; r0 < 4; ++r0)
#pragma unroll
    for (int j = 0; j < 4; ++j) {
      Os[ql * 68 + hi * 4 + r0 * 8 + j]      = (__bf16)(oA[r0 * 4 + j]);
      Os[ql * 68 + 32 + hi * 4 + r0 * 8 + j] = (__bf16)(oB[r0 * 4 + j]);
    }
  __syncthreads();
  __bf16* Op = kvh ? Op1 : Op0;
  const int sub = t & 7, rid0 = t >> 3;
#pragma unroll
  for (int p = 0; p < 4; ++p) {
    const int rid = p * 32 + rid0;
    const bf16x8 v = *(const bf16x8*)&Os[rid * 68 + sub * 8];
    *(bf16x8*)(Op + ((size_t)(b * Ss + q0blk + rid)) * Uu + h * 64 + sub * 8) = v;
  }
}

// ---------- combine split-KV partials: O = (O0 + O1) / (l0 + l1) ----------
__global__ __launch_bounds__(256) void k_combine(const __bf16* __restrict__ Op0, const __bf16* __restrict__ Op1,
                                                 const float* __restrict__ Lp, __bf16* __restrict__ Og) {
  const size_t idx = (size_t)blockIdx.x * 256 + threadIdx.x;   // bf16x8 group id
  const size_t e0 = idx * 8;
  const int row = (int)(e0 >> 10);          // (b*2048 + s)
  const int d = (int)(e0 & 1023);
  const int b = row >> 11, s = row & 2047, h = d >> 6;
  const size_t lidx = ((size_t)(b * 16 + h)) * 2048 + s;
  const float rl = 1.0f / (Lp[lidx] + Lp[65536 + lidx]);
  const bf16x8 a = *(const bf16x8*)(Op0 + e0);
  const bf16x8 c = *(const bf16x8*)(Op1 + e0);
  bf16x8 o;
#pragma unroll
  for (int j = 0; j < 8; ++j) o[j] = (__bf16)(((float)a[j] + (float)c[j]) * rl);
  *(bf16x8*)(Og + e0) = o;
}

__global__ __launch_bounds__(256) void k_ln_stats(const float* __restrict__ partials, float* __restrict__ stats) {
  const int row = blockIdx.x * 256 + threadIdx.x;
  float s = 0.f, q = 0.f;
#pragma unroll
  for (int c = 0; c < 16; ++c) {
    s += partials[((size_t)row * 16 + c) * 2];
    q += partials[((size_t)row * 16 + c) * 2 + 1];
  }
  const float mean = s * (1.0f / 1024.0f);
  const float var = q * (1.0f / 1024.0f) - mean * mean;
  stats[row * 2] = mean;
  stats[row * 2 + 1] = rsqrtf(var + 1e-5f);
}

// ---------- normalize + transpose to (B,D,S) f32; Wb is bf16 ----------
__global__ __launch_bounds__(256) void k_ln_write(const __bf16* __restrict__ Wb, const float* __restrict__ stats,
                                                  const float* __restrict__ gamma, const float* __restrict__ beta,
                                                  float* __restrict__ out) {
  __shared__ __attribute__((aligned(16))) float ws0[64][65];
  __shared__ float sm[64][2];
  const int d0 = blockIdx.x * 64, s0 = blockIdx.y * 64, b = blockIdx.z;
  const int t = threadIdx.x;
  {
    const int sl = t >> 2, dc = (t & 3) * 16;
    const __bf16* src = Wb + ((size_t)(b * Ss + s0 + sl)) * Dd + d0 + dc;
    const bf16x8 f0 = *(const bf16x8*)src;
    const bf16x8 f1 = *(const bf16x8*)(src + 8);
#pragma unroll
    for (int j = 0; j < 8; ++j) { ws0[dc + j][sl] = (float)f0[j]; ws0[dc + 8 + j][sl] = (float)f1[j]; }
  }
  if (t < 128) sm[t >> 1][t & 1] = stats[(size_t)(b * Ss + s0 + (t >> 1)) * 2 + (t & 1)];
  __syncthreads();
  const int dl = t >> 2, sc = (t & 3) * 16;
  const float g = gamma[d0 + dl], be = beta[d0 + dl];
  float* dst = out + ((size_t)(b * Dd + d0 + dl)) * Ss + s0 + sc;
#pragma unroll
  for (int q = 0; q < 4; ++q) {
    float4 o;
    o.x = (ws0[dl][sc + q * 4 + 0] - sm[sc + q * 4 + 0][0]) * sm[sc + q * 4 + 0][1] * g + be;
    o.y = (ws0[dl][sc + q * 4 + 1] - sm[sc + q * 4 + 1][0]) * sm[sc + q * 4 + 1][1] * g + be;
    o.z = (ws0[dl][sc + q * 4 + 2] - sm[sc + q * 4 + 2][0]) * sm[sc + q * 4 + 2][1] * g + be;
    o.w = (ws0[dl][sc + q * 4 + 3] - sm[sc + q * 4 + 3][0]) * sm[sc + q * 4 + 3][1] * g + be;
    *(float4*)(dst + q * 4) = o;
  }
}

extern "C" void kernel_launch(void* const* d_in, const int* in_sizes, int n_in,
                              void* d_out, int out_size, void* d_ws, size_t ws_size,
                              hipStream_t stream) {
  const float* inp   = (const float*)d_in[0];
  const float* Wq    = (const float*)d_in[1];
  const float* bq    = (const float*)d_in[2];
  const float* Wk    = (const float*)d_in[3];
  const float* bk    = (const float*)d_in[4];
  const float* Wv    = (const float*)d_in[5];
  const float* bv    = (const float*)d_in[6];
  const float* Wo    = (const float*)d_in[7];
  const float* bo    = (const float*)d_in[8];
  const float* gamma = (const float*)d_in[9];
  const float* beta  = (const float*)d_in[10];

  char* ws = (char*)d_ws;
  const size_t MB = 1ull << 20;
  __bf16* xb  = (__bf16*)(ws);             // 8 MB   (B,S,D) bf16 (GEMM A + residual source)
  __bf16* Wqt = (__bf16*)(ws + 8 * MB);    // 2 MB each, [n][k] bf16
  __bf16* Wkt = (__bf16*)(ws + 10 * MB);
  __bf16* Wvt = (__bf16*)(ws + 12 * MB);
  __bf16* Wot = (__bf16*)(ws + 14 * MB);
  __bf16* Qb  = (__bf16*)(ws + 16 * MB);   // 8 MB, (B,H,S,64)
  __bf16* Kb  = (__bf16*)(ws + 24 * MB);   // 8 MB, (B,H,S,64)
  __bf16* Vtb = (__bf16*)(ws + 32 * MB);   // 8 MB, (B,H,64,S)  V^T
  __bf16* Op0 = (__bf16*)(ws + 40 * MB);   // 8 MB unnormalized O, kv-half 0
  __bf16* Op1 = (__bf16*)(ws + 48 * MB);   // 8 MB unnormalized O, kv-half 1
  __bf16* Onr = (__bf16*)(ws + 56 * MB);   // 8 MB normalized O (B,S,U)
  float*  Lp  = (float*)(ws + 9 * MB);     // 512 KB, 2 x 65536 f32 (aliases dead Wqt tail)
  __bf16* Wb  = (__bf16*)(ws + 16 * MB);   // 8 MB bf16, aliases dead Qb
  float*  partials = (float*)(ws + 8 * MB);            // 512 KB (dead Wqt head)
  float*  stats    = (float*)(ws + 8 * MB + 512 * 1024);

  k_xpose_x<<<dim3(32, 16, 2), 256, 0, stream>>>(inp, xb);
  k_xpose_w<<<dim3(16, 16, 4), 256, 0, stream>>>(Wq, Wk, Wv, Wo, Wqt, Wkt, Wvt, Wot);
  k_gemm_qkv8<<<dim3(192), 512, 0, stream>>>(xb, Wqt, Wkt, Wvt, bq, bk, bv, Qb, Kb, Vtb);
  k_attn9<<<dim3(1024), 256, 0, stream>>>(Qb, Kb, Vtb, Op0, Op1, Lp);
  k_combine<<<dim3(2048), 256, 0, stream>>>(Op0, Op1, Lp, Onr);
  k_gemm_o<<<dim3(256), 256, 0, stream>>>(Onr, Wot, bo, xb, Wb, partials);
  k_ln_stats<<<dim3(16), 256, 0, stream>>>(partials, stats);
  k_ln_write<<<dim3(16, 32, 2), 256, 0, stream>>>(Wb, stats, gamma, beta, (float*)d_out);
}

// Round 12
// 133.740 us; speedup vs baseline: 1.1792x; 1.1792x over previous
//
#include <hip/hip_runtime.h>
#include <hip/hip_bf16.h>

typedef __bf16 bf16x8 __attribute__((ext_vector_type(8)));
typedef __bf16 bf16x4 __attribute__((ext_vector_type(4)));
typedef float  f32x4  __attribute__((ext_vector_type(4)));
typedef float  f32x16 __attribute__((ext_vector_type(16)));

#define MFMA16(a, b, c) __builtin_amdgcn_mfma_f32_16x16x32_bf16((a), (b), (c), 0, 0, 0)
#define MFMA32(a, b, c) __builtin_amdgcn_mfma_f32_32x32x16_bf16((a), (b), (c), 0, 0, 0)

namespace {
constexpr int Bb = 2, Dd = 1024, Ss = 2048, Uu = 1024, Hh = 16;
}

#if __has_builtin(__builtin_amdgcn_exp2f)
#define EXP2(x) __builtin_amdgcn_exp2f(x)
#else
#define EXP2(x) __expf((x) * 0.6931471805599453f)
#endif

__device__ __forceinline__ uint32_t pkbf(float a, float b) {
  union { __bf16 h[2]; uint32_t u; } z;
  z.h[0] = (__bf16)a; z.h[1] = (__bf16)b;
  return z.u;
}
#define PLSWAP(a, b) asm("v_permlane32_swap_b32 %0, %1" : "+v"(a), "+v"(b))

__device__ __forceinline__ void gl16(const void* g, void* l) {
  __builtin_amdgcn_global_load_lds((const __attribute__((address_space(1))) uint32_t*)g,
                                   (__attribute__((address_space(3))) uint32_t*)l, 16, 0, 0);
}

#define VMW(n) asm volatile("s_waitcnt vmcnt(" #n ")" ::: "memory")
#define BARRIER_PIN() do { __builtin_amdgcn_s_barrier(); \
  asm volatile("" ::: "memory"); __builtin_amdgcn_sched_barrier(0); } while (0)
#define LGKM0() asm volatile("s_waitcnt lgkmcnt(0)" ::: "memory")

// ---------- transpose x: (B,D,S) f32 -> xb (B,S,D) bf16 ----------
__global__ __launch_bounds__(256) void k_xpose_x(const float* __restrict__ inp,
                                                 __bf16* __restrict__ xb) {
  __shared__ __attribute__((aligned(16))) __bf16 ts[64][72];
  const int s0 = blockIdx.x * 64, d0 = blockIdx.y * 64, b = blockIdx.z;
  const int t = threadIdx.x;
  {
    const int i = t >> 2, c = (t & 3) * 16;
    const float* src = inp + ((size_t)(b * Dd + d0 + i)) * Ss + s0 + c;
#pragma unroll
    for (int q = 0; q < 4; ++q) {
      const float4 f = *(const float4*)(src + q * 4);
      ts[i][c + q * 4 + 0] = (__bf16)f.x;
      ts[i][c + q * 4 + 1] = (__bf16)f.y;
      ts[i][c + q * 4 + 2] = (__bf16)f.z;
      ts[i][c + q * 4 + 3] = (__bf16)f.w;
    }
  }
  __syncthreads();
  {
    const int sl = t >> 2, dc = (t & 3) * 16;
    bf16x8 va, vb;
#pragma unroll
    for (int j = 0; j < 8; ++j) { va[j] = ts[dc + j][sl]; vb[j] = ts[dc + 8 + j][sl]; }
    __bf16* dst = xb + ((size_t)(b * Ss + s0 + sl)) * Dd + d0 + dc;
    *(bf16x8*)dst = va;
    *(bf16x8*)(dst + 8) = vb;
  }
}

// ---------- transpose weights: (K,N) f32 -> (N,K) bf16, 4 matrices ----------
__global__ __launch_bounds__(256) void k_xpose_w(const float* __restrict__ w0, const float* __restrict__ w1,
                                                 const float* __restrict__ w2, const float* __restrict__ w3,
                                                 __bf16* __restrict__ o0, __bf16* __restrict__ o1,
                                                 __bf16* __restrict__ o2, __bf16* __restrict__ o3) {
  __shared__ __attribute__((aligned(16))) __bf16 ts[64][72];
  const float* src_m; __bf16* dst_m;
  switch (blockIdx.z) {
    case 0: src_m = w0; dst_m = o0; break;
    case 1: src_m = w1; dst_m = o1; break;
    case 2: src_m = w2; dst_m = o2; break;
    default: src_m = w3; dst_m = o3; break;
  }
  const int n0 = blockIdx.x * 64, k0 = blockIdx.y * 64;
  const int t = threadIdx.x;
  {
    const int i = t >> 2, c = (t & 3) * 16;
    const float* src = src_m + (size_t)(k0 + i) * 1024 + n0 + c;
#pragma unroll
    for (int q = 0; q < 4; ++q) {
      const float4 f = *(const float4*)(src + q * 4);
      ts[i][c + q * 4 + 0] = (__bf16)f.x;
      ts[i][c + q * 4 + 1] = (__bf16)f.y;
      ts[i][c + q * 4 + 2] = (__bf16)f.z;
      ts[i][c + q * 4 + 3] = (__bf16)f.w;
    }
  }
  __syncthreads();
  {
    const int nl = t >> 2, kc = (t & 3) * 16;
    bf16x8 va, vb;
#pragma unroll
    for (int j = 0; j < 8; ++j) { va[j] = ts[kc + j][nl]; vb[j] = ts[kc + 8 + j][nl]; }
    __bf16* dst = dst_m + (size_t)(n0 + nl) * 1024 + k0 + kc;
    *(bf16x8*)dst = va;
    *(bf16x8*)(dst + 8) = vb;
  }
}

// ---------- 256x256-tile QKV GEMM: 4-slot LDS ring, counted vmcnt, swizzled ----------
__global__ __launch_bounds__(512, 2) void k_gemm_qkv8(const __bf16* __restrict__ A,
    const __bf16* __restrict__ W0, const __bf16* __restrict__ W1, const __bf16* __restrict__ W2,
    const float* __restrict__ b0, const float* __restrict__ b1, const float* __restrict__ b2,
    __bf16* __restrict__ Qb, __bf16* __restrict__ Kb, __bf16* __restrict__ Vt) {
  __shared__ __attribute__((aligned(16))) __bf16 As[4][256][32];
  __shared__ __attribute__((aligned(16))) __bf16 Bs[4][256][32];
  const int t = threadIdx.x;
  const int w = t >> 6, l = t & 63, lg = l >> 4, lr = l & 15;
  const int wm = w >> 2, wn = w & 3;
  const int bid = blockIdx.x;
  const int logical = (bid & 7) * 24 + (bid >> 3);
  const int z = logical >> 6;
  const int rem = logical & 63;
  const int n0 = (rem & 3) * 256, m0 = (rem >> 2) * 256;
  const __bf16* Bt = z == 0 ? W0 : z == 1 ? W1 : W2;
  const float* bias = z == 0 ? b0 : z == 1 ? b1 : b2;

  const int srow = t >> 2, sc8 = t & 3, scol = sc8 * 8;
  const int so = ((sc8 + 4 - ((srow >> 1) & 3)) & 3) * 8;
  const __bf16* gaB = A  + ((size_t)(m0 + srow)) * 1024 + so;
  const __bf16* gbB = Bt + ((size_t)(n0 + srow)) * 1024 + so;
#define STG_A(s, h, kt) gl16(gaB + (size_t)(h) * 128 * 1024 + (kt) * 32, &As[s][(h) * 128 + srow][scol])
#define STG_B(s, h, kt) gl16(gbB + (size_t)(h) * 128 * 1024 + (kt) * 32, &Bs[s][(h) * 128 + srow][scol])

  STG_A(0, 0, 0); STG_A(0, 1, 0); STG_B(0, 0, 0); STG_B(0, 1, 0);
  STG_A(1, 0, 1); STG_A(1, 1, 1); STG_B(1, 0, 1); STG_B(1, 1, 1);
  STG_A(2, 0, 2); STG_A(2, 1, 2); STG_B(2, 0, 2); STG_B(2, 1, 2);
  f32x4 acc[8][4] = {};
  VMW(8);
  BARRIER_PIN();

  const int rdc = ((lg + (lr >> 1)) & 3) * 8;
  const __bf16* Abase = &As[0][0][0] + wm * 4096 + lr * 32 + rdc;
  const __bf16* Bbase = &Bs[0][0][0] + wn * 2048 + lr * 32 + rdc;

  for (int kt = 0; kt < 32; ++kt) {
    const int sC = kt & 3, sS = (kt + 3) & 3;
    const __bf16* Ap = Abase + sC * 8192;
    const __bf16* Bp = Bbase + sC * 8192;
    bf16x8 a0, a1, a2, a3, bb0, bb1, bb2, bb3;
    a0 = *(const bf16x8*)(Ap);         a1 = *(const bf16x8*)(Ap + 512);
    a2 = *(const bf16x8*)(Ap + 1024);  a3 = *(const bf16x8*)(Ap + 1536);
    bb0 = *(const bf16x8*)(Bp);        bb1 = *(const bf16x8*)(Bp + 512);
    bb2 = *(const bf16x8*)(Bp + 1024); bb3 = *(const bf16x8*)(Bp + 1536);
    if (kt < 29) { STG_A(sS, 0, kt + 3); STG_A(sS, 1, kt + 3); }
    BARRIER_PIN();
    LGKM0(); __builtin_amdgcn_sched_barrier(0);
    __builtin_amdgcn_s_setprio(1);
    acc[0][0] = MFMA16(a0, bb0, acc[0][0]); acc[0][1] = MFMA16(a0, bb1, acc[0][1]);
    acc[0][2] = MFMA16(a0, bb2, acc[0][2]); acc[0][3] = MFMA16(a0, bb3, acc[0][3]);
    acc[1][0] = MFMA16(a1, bb0, acc[1][0]); acc[1][1] = MFMA16(a1, bb1, acc[1][1]);
    acc[1][2] = MFMA16(a1, bb2, acc[1][2]); acc[1][3] = MFMA16(a1, bb3, acc[1][3]);
    acc[2][0] = MFMA16(a2, bb0, acc[2][0]); acc[2][1] = MFMA16(a2, bb1, acc[2][1]);
    acc[2][2] = MFMA16(a2, bb2, acc[2][2]); acc[2][3] = MFMA16(a2, bb3, acc[2][3]);
    acc[3][0] = MFMA16(a3, bb0, acc[3][0]); acc[3][1] = MFMA16(a3, bb1, acc[3][1]);
    acc[3][2] = MFMA16(a3, bb2, acc[3][2]); acc[3][3] = MFMA16(a3, bb3, acc[3][3]);
    __builtin_amdgcn_s_setprio(0);
    BARRIER_PIN();
    a0 = *(const bf16x8*)(Ap + 2048);  a1 = *(const bf16x8*)(Ap + 2560);
    a2 = *(const bf16x8*)(Ap + 3072);  a3 = *(const bf16x8*)(Ap + 3584);
    if (kt < 29) { STG_B(sS, 0, kt + 3); STG_B(sS, 1, kt + 3); }
    if (kt < 29) { VMW(8); } else if (kt == 29) { VMW(4); } else if (kt == 30) { VMW(0); }
    BARRIER_PIN();
    LGKM0(); __builtin_amdgcn_sched_barrier(0);
    __builtin_amdgcn_s_setprio(1);
    acc[4][0] = MFMA16(a0, bb0, acc[4][0]); acc[4][1] = MFMA16(a0, bb1, acc[4][1]);
    acc[4][2] = MFMA16(a0, bb2, acc[4][2]); acc[4][3] = MFMA16(a0, bb3, acc[4][3]);
    acc[5][0] = MFMA16(a1, bb0, acc[5][0]); acc[5][1] = MFMA16(a1, bb1, acc[5][1]);
    acc[5][2] = MFMA16(a1, bb2, acc[5][2]); acc[5][3] = MFMA16(a1, bb3, acc[5][3]);
    acc[6][0] = MFMA16(a2, bb0, acc[6][0]); acc[6][1] = MFMA16(a2, bb1, acc[6][1]);
    acc[6][2] = MFMA16(a2, bb2, acc[6][2]); acc[6][3] = MFMA16(a2, bb3, acc[6][3]);
    acc[7][0] = MFMA16(a3, bb0, acc[7][0]); acc[7][1] = MFMA16(a3, bb1, acc[7][1]);
    acc[7][2] = MFMA16(a3, bb2, acc[7][2]); acc[7][3] = MFMA16(a3, bb3, acc[7][3]);
    __builtin_amdgcn_s_setprio(0);
    BARRIER_PIN();
  }
#undef STG_A
#undef STG_B

  const int b = m0 >> 11, sb = m0 & 2047;
  __bf16* Ct = &As[0][0][0];
  float bi[4];
#pragma unroll
  for (int j = 0; j < 4; ++j) bi[j] = bias[n0 + wn * 64 + j * 16 + lr];
  if (z < 2) {
    __bf16* out = z == 0 ? Qb : Kb;
    const float scale = z == 0 ? 0.125f * 1.44269504f : 1.0f;
    const int h0 = n0 >> 6;
    for (int c = 0; c < 4; ++c) {
      __syncthreads();
      if (wm == (c >> 1)) {
        const int q = c & 1;
#pragma unroll
        for (int j = 0; j < 4; ++j) {
          const int nl = wn * 64 + j * 16 + lr;
#pragma unroll
          for (int i2 = 0; i2 < 4; ++i2)
#pragma unroll
            for (int r = 0; r < 4; ++r)
              Ct[(i2 * 16 + lg * 4 + r) * 264 + nl] =
                  (__bf16)(fmaxf(acc[q * 4 + i2][j][r] + bi[j], 0.0f) * scale);
        }
      }
      __syncthreads();
#pragma unroll
      for (int u4 = 0; u4 < 4; ++u4) {
        const int u = u4 * 512 + t;
        const int sl = u >> 5, ru = u & 31;
        const int hh = ru >> 3, sg = ru & 7;
        const bf16x8 v = *(const bf16x8*)&Ct[sl * 264 + hh * 64 + sg * 8];
        *(bf16x8*)(out + ((size_t)(b * Hh + h0 + hh) * Ss + sb + c * 64 + sl) * 64 + sg * 8) = v;
      }
    }
  } else {
    for (int c = 0; c < 4; ++c) {
      __syncthreads();
      if (wn == c) {
#pragma unroll
        for (int j = 0; j < 4; ++j) {
          const int nli = j * 16 + lr;
#pragma unroll
          for (int mi = 0; mi < 8; ++mi)
#pragma unroll
            for (int r2 = 0; r2 < 4; r2 += 2) {
              const int ml = wm * 128 + mi * 16 + lg * 4 + r2;
              const uint32_t pk = pkbf(fmaxf(acc[mi][j][r2] + bi[j], 0.0f),
                                       fmaxf(acc[mi][j][r2 + 1] + bi[j], 0.0f));
              *(uint32_t*)&Ct[nli * 264 + ml] = pk;
            }
        }
      }
      __syncthreads();
#pragma unroll
      for (int u4 = 0; u4 < 4; ++u4) {
        const int u = u4 * 512 + t;
        const int nl = u >> 5, sg = u & 31;
        const bf16x8 v = *(const bf16x8*)&Ct[nl * 264 + sg * 8];
        *(bf16x8*)(Vt + (size_t)(b * 1024 + n0 + c * 64 + nl) * Ss + sb + sg * 8) = v;
      }
    }
  }
}

// ---------- 128x128 GEMM core (Wo): 3-buffer depth-2 counted-vmcnt ----------
__device__ __forceinline__ int swz_slot(int row, int slot) { return (slot + (row >> 1)) & 3; }

__device__ __forceinline__ void gemm_core(const __bf16* __restrict__ A, const __bf16* __restrict__ Bt,
                                          __bf16 (*__restrict__ As)[128][32], __bf16 (*__restrict__ Bs)[128][32],
                                          int m0, int n0, int t, f32x4 acc[4][4]) {
  const int w = t >> 6, l = t & 63;
  const int wm = (w >> 1) * 64, wn = (w & 1) * 64;
  const int lg = l >> 4, lr = l & 15;
  const int sr = t >> 2, sc8 = t & 3;
  const int so = ((sc8 + 4 - ((sr >> 1) & 3)) & 3) * 8;
  const __bf16* ga = A + (size_t)(m0 + sr) * 1024 + so;
  const __bf16* gb = Bt + (size_t)(n0 + sr) * 1024 + so;
  const int de = sr * 32 + sc8 * 8;
#define STG(bf, kk) { \
    gl16(ga + (kk) * 32,             &As[bf][0][0] + de); \
    gl16(ga + (kk) * 32 + 64 * 1024, &As[bf][0][0] + de + 64 * 32); \
    gl16(gb + (kk) * 32,             &Bs[bf][0][0] + de); \
    gl16(gb + (kk) * 32 + 64 * 1024, &Bs[bf][0][0] + de + 64 * 32); }
  STG(0, 0) STG(1, 1)
  for (int s = 0; s < 32; ++s) {
    if (s < 31) { VMW(4); } else { VMW(0); }
    BARRIER_PIN();
    if (s + 2 < 32) { const int b2 = (s + 2) % 3; STG(b2, s + 2) }
    const int cb = s % 3;
    bf16x8 af[4], bfr[4];
#pragma unroll
    for (int i = 0; i < 4; ++i) { const int rr = wm + i * 16 + lr; af[i]  = *(const bf16x8*)&As[cb][rr][swz_slot(rr, lg) * 8]; }
#pragma unroll
    for (int i = 0; i < 4; ++i) { const int rr = wn + i * 16 + lr; bfr[i] = *(const bf16x8*)&Bs[cb][rr][swz_slot(rr, lg) * 8]; }
#pragma unroll
    for (int i = 0; i < 4; ++i)
#pragma unroll
      for (int j = 0; j < 4; ++j) acc[i][j] = MFMA16(af[i], bfr[j], acc[i][j]);
  }
#undef STG
}

// Wo GEMM + residual(from xb bf16) + LN partial stats; Wb output bf16.
__global__ __launch_bounds__(256) void k_gemm_o(const __bf16* __restrict__ A, const __bf16* __restrict__ Bt,
                                                const float* __restrict__ bias, const __bf16* __restrict__ xb,
                                                __bf16* __restrict__ Wb, float* __restrict__ partials) {
  __shared__ __attribute__((aligned(16))) char smem[49152];
  auto As = (__bf16 (*)[128][32])smem;
  auto Bs = (__bf16 (*)[128][32])(smem + 24576);
  float* Cs = (float*)smem;  // [64][132] f32
  const int flat = blockIdx.x;
  const int logical = (flat & 7) * 32 + (flat >> 3);
  const int n0 = (logical & 7) * 128, m0 = (logical >> 3) * 128;
  const int t = threadIdx.x, w = t >> 6, l = t & 63;
  const int wm = (w >> 1) * 64, wn = (w & 1) * 64;
  const int lg = l >> 4, lr = l & 15;
  f32x4 acc[4][4] = {};
  gemm_core(A, Bt, As, Bs, m0, n0, t, acc);
  const int sub = t & 31, rid0 = t >> 5;
#pragma unroll
  for (int h2 = 0; h2 < 2; ++h2) {
    __syncthreads();
    if ((w >> 1) == h2) {
#pragma unroll
      for (int j = 0; j < 4; ++j) {
        const int nl = wn + j * 16 + lr;
        const float bi = bias[n0 + nl];
#pragma unroll
        for (int i = 0; i < 4; ++i)
#pragma unroll
          for (int r = 0; r < 4; ++r)
            Cs[(i * 16 + lg * 4 + r) * 132 + nl] = acc[i][j][r] + bi;
      }
    }
    __syncthreads();
#pragma unroll
    for (int p = 0; p < 8; ++p) {
      const int row = p * 8 + rid0;
      const int m = m0 + h2 * 64 + row;
      float4 v = *(const float4*)&Cs[row * 132 + sub * 4];
      const bf16x4 x4 = *(const bf16x4*)&xb[(size_t)m * 1024 + n0 + sub * 4];
      v.x += (float)x4[0]; v.y += (float)x4[1]; v.z += (float)x4[2]; v.w += (float)x4[3];
      bf16x4 pv;
      pv[0] = (__bf16)v.x; pv[1] = (__bf16)v.y; pv[2] = (__bf16)v.z; pv[3] = (__bf16)v.w;
      *(bf16x4*)&Wb[(size_t)m * 1024 + n0 + sub * 4] = pv;
      float s = v.x + v.y + v.z + v.w;
      float q = v.x * v.x + v.y * v.y + v.z * v.z + v.w * v.w;
      s += __shfl_xor(s, 1); s += __shfl_xor(s, 2); s += __shfl_xor(s, 4); s += __shfl_xor(s, 8);
      q += __shfl_xor(q, 1); q += __shfl_xor(q, 2); q += __shfl_xor(q, 4); q += __shfl_xor(q, 8);
      if ((sub & 15) == 0) {
        const int ci = (n0 >> 6) + (sub >> 4);
        partials[((size_t)m * 16 + ci) * 2]     = s;
        partials[((size_t)m * 16 + ci) * 2 + 1] = q;
      }
    }
  }
}

// ---------- flash attention (r8-best): max-free softmax, raw-barrier pipeline,
// coalesced O-write, + T5 setprio (m191 regime: 2 independent blocks/CU) ----------
__global__ __launch_bounds__(256, 2) void k_attn6(const __bf16* __restrict__ Qg, const __bf16* __restrict__ Kg,
                                                  const __bf16* __restrict__ Vt, __bf16* __restrict__ Og) {
  __shared__ __attribute__((aligned(16))) char smem[36864];
  auto Ks = (__bf16 (*)[64][72])smem;
  auto Vs = (__bf16 (*)[64][72])(smem + 18432);
  __bf16* Os = (__bf16*)smem;
  const int t = threadIdx.x, l = t & 63, w = t >> 6;
  const int ln = l & 31, hi = l >> 5;
  const int bid = blockIdx.x;
  const int orig = (bid & 7) * 64 + (bid >> 3);
  const int bh = orig >> 4, qt = orig & 15;
  const int q0blk = qt * 128;
  const int q0w = q0blk + w * 32;
  const int b = bh >> 4, h = bh & 15;
  const size_t kbase = (size_t)bh * Ss * 64;
  const int srow = t >> 2, scol = (t & 3) * 16;
  const __bf16* Krow = Kg + kbase + (size_t)srow * 64 + scol;
  const __bf16* Vrow = Vt + (size_t)(bh * 64 + srow) * Ss + scol;

  bf16x8 qf0, qf1, qf2, qf3;
  {
    const __bf16* qp = Qg + kbase + (size_t)(q0w + ln) * 64 + hi * 8;
    qf0 = *(const bf16x8*)(qp);
    qf1 = *(const bf16x8*)(qp + 16);
    qf2 = *(const bf16x8*)(qp + 32);
    qf3 = *(const bf16x8*)(qp + 48);
  }
  f32x16 oA = {}, oB = {};
  float lrow = 0.f;

  auto tile_compute = [&](const __bf16 (&K)[64][72], const __bf16 (&V)[64][72]) {
    f32x16 s0 = {}, s1 = {};
    __builtin_amdgcn_s_setprio(1);
    {
      bf16x8 kf;
#define QK(u, cc, sacc) \
      kf = *(const bf16x8*)&K[(u) * 32 + ln][(cc) * 16 + hi * 8]; \
      sacc = MFMA32(kf, qf##cc, sacc);
      QK(0, 0, s0) QK(0, 1, s0) QK(0, 2, s0) QK(0, 3, s0)
      QK(1, 0, s1) QK(1, 1, s1) QK(1, 2, s1) QK(1, 3, s1)
#undef QK
    }
    __builtin_amdgcn_s_setprio(0);
#pragma unroll
    for (int r = 0; r < 16; ++r) s0[r] = EXP2(s0[r]);
#pragma unroll
    for (int r = 0; r < 16; ++r) s1[r] = EXP2(s1[r]);
    float sm[16];
#pragma unroll
    for (int r = 0; r < 8; ++r) sm[r] = s0[2 * r] + s0[2 * r + 1];
#pragma unroll
    for (int r = 0; r < 8; ++r) sm[8 + r] = s1[2 * r] + s1[2 * r + 1];
#pragma unroll
    for (int st = 8; st > 0; st >>= 1)
#pragma unroll
      for (int r = 0; r < st; ++r) sm[r] += sm[r + st];
    lrow += sm[0];
    uint32_t w0[8], w1[8];
#pragma unroll
    for (int k = 0; k < 8; ++k) w0[k] = pkbf(s0[2 * k], s0[2 * k + 1]);
#pragma unroll
    for (int k = 0; k < 8; ++k) w1[k] = pkbf(s1[2 * k], s1[2 * k + 1]);
    PLSWAP(w0[0], w0[2]); PLSWAP(w0[1], w0[3]);
    PLSWAP(w0[4], w0[6]); PLSWAP(w0[5], w0[7]);
    PLSWAP(w1[0], w1[2]); PLSWAP(w1[1], w1[3]);
    PLSWAP(w1[4], w1[6]); PLSWAP(w1[5], w1[7]);
    union U4 { uint32_t u[4]; bf16x8 v; };
    U4 z;
    bf16x8 pa0, pa1, pa2, pa3;
    z.u[0] = w0[0]; z.u[1] = w0[1]; z.u[2] = w0[2]; z.u[3] = w0[3]; pa0 = z.v;
    z.u[0] = w0[4]; z.u[1] = w0[5]; z.u[2] = w0[6]; z.u[3] = w0[7]; pa1 = z.v;
    z.u[0] = w1[0]; z.u[1] = w1[1]; z.u[2] = w1[2]; z.u[3] = w1[3]; pa2 = z.v;
    z.u[0] = w1[4]; z.u[1] = w1[5]; z.u[2] = w1[6]; z.u[3] = w1[7]; pa3 = z.v;
    __builtin_amdgcn_s_setprio(1);
    {
      bf16x8 vf;
#define PV(half, ti, pa, oacc) \
      vf = *(const bf16x8*)&V[(half) * 32 + ln][(ti) * 16 + hi * 8]; \
      oacc = MFMA32(vf, pa, oacc);
      PV(0, 0, pa0, oA) PV(0, 1, pa1, oA) PV(0, 2, pa2, oA) PV(0, 3, pa3, oA)
      PV(1, 0, pa0, oB) PV(1, 1, pa1, oB) PV(1, 2, pa2, oB) PV(1, 3, pa3, oB)
#undef PV
    }
    __builtin_amdgcn_s_setprio(0);
  };

  bf16x8 kA0 = *(const bf16x8*)(Krow),      kA1 = *(const bf16x8*)(Krow + 8);
  bf16x8 vA0 = *(const bf16x8*)(Vrow),      vA1 = *(const bf16x8*)(Vrow + 8);
  bf16x8 kB0 = *(const bf16x8*)(Krow + 64 * 64), kB1 = *(const bf16x8*)(Krow + 64 * 64 + 8);
  bf16x8 vB0 = *(const bf16x8*)(Vrow + 64), vB1 = *(const bf16x8*)(Vrow + 64 + 8);

  for (int tt = 0; tt < 16; ++tt) {
    *(bf16x8*)&Ks[0][srow][scol]     = kA0;
    *(bf16x8*)&Ks[0][srow][scol + 8] = kA1;
    *(bf16x8*)&Vs[0][srow][scol]     = vA0;
    *(bf16x8*)&Vs[0][srow][scol + 8] = vA1;
    LGKM0();
    BARRIER_PIN();
    if (tt < 15) {
      const size_t ko = (size_t)(2 * tt + 2) * 64;
      kA0 = *(const bf16x8*)(Krow + ko * 64);
      kA1 = *(const bf16x8*)(Krow + ko * 64 + 8);
      vA0 = *(const bf16x8*)(Vrow + ko);
      vA1 = *(const bf16x8*)(Vrow + ko + 8);
    }
    tile_compute(Ks[0], Vs[0]);
    *(bf16x8*)&Ks[1][srow][scol]     = kB0;
    *(bf16x8*)&Ks[1][srow][scol + 8] = kB1;
    *(bf16x8*)&Vs[1][srow][scol]     = vB0;
    *(bf16x8*)&Vs[1][srow][scol + 8] = vB1;
    LGKM0();
    BARRIER_PIN();
    if (tt < 15) {
      const size_t ko = (size_t)(2 * tt + 3) * 64;
      kB0 = *(const bf16x8*)(Krow + ko * 64);
      kB1 = *(const bf16x8*)(Krow + ko * 64 + 8);
      vB0 = *(const bf16x8*)(Vrow + ko);
      vB1 = *(const bf16x8*)(Vrow + ko + 8);
    }
    tile_compute(Ks[1], Vs[1]);
  }
  {
    uint32_t a = __builtin_bit_cast(uint32_t, lrow), bsw = a;
    PLSWAP(a, bsw);
    lrow = __builtin_bit_cast(float, a) + __builtin_bit_cast(float, bsw);
  }
  const float rl = 1.0f / lrow;
  __syncthreads();
  const int ql = w * 32 + ln;
#pragma unroll
  for (int r0 = 0; r0 < 4; ++r0)
#pragma unroll
    for (int j = 0; j < 4; ++j) {
      Os[ql * 68 + hi * 4 + r0 * 8 + j]      = (__bf16)(oA[r0 * 4 + j] * rl);
      Os[ql * 68 + 32 + hi * 4 + r0 * 8 + j] = (__bf16)(oB[r0 * 4 + j] * rl);
    }
  __syncthreads();
  const int sub = t & 7, rid0 = t >> 3;
#pragma unroll
  for (int p = 0; p < 4; ++p) {
    const int rid = p * 32 + rid0;
    const bf16x8 v = *(const bf16x8*)&Os[rid * 68 + sub * 8];
    *(bf16x8*)(Og + ((size_t)(b * Ss + q0blk + rid)) * Uu + h * 64 + sub * 8) = v;
  }
}

__global__ __launch_bounds__(256) void k_ln_stats(const float* __restrict__ partials, float* __restrict__ stats) {
  const int row = blockIdx.x * 256 + threadIdx.x;
  float s = 0.f, q = 0.f;
#pragma unroll
  for (int c = 0; c < 16; ++c) {
    s += partials[((size_t)row * 16 + c) * 2];
    q += partials[((size_t)row * 16 + c) * 2 + 1];
  }
  const float mean = s * (1.0f / 1024.0f);
  const float var = q * (1.0f / 1024.0f) - mean * mean;
  stats[row * 2] = mean;
  stats[row * 2 + 1] = rsqrtf(var + 1e-5f);
}

// ---------- normalize + transpose to (B,D,S) f32; Wb is bf16 ----------
__global__ __launch_bounds__(256) void k_ln_write(const __bf16* __restrict__ Wb, const float* __restrict__ stats,
                                                  const float* __restrict__ gamma, const float* __restrict__ beta,
                                                  float* __restrict__ out) {
  __shared__ __attribute__((aligned(16))) float ws0[64][65];
  __shared__ float sm[64][2];
  const int d0 = blockIdx.x * 64, s0 = blockIdx.y * 64, b = blockIdx.z;
  const int t = threadIdx.x;
  {
    const int sl = t >> 2, dc = (t & 3) * 16;
    const __bf16* src = Wb + ((size_t)(b * Ss + s0 + sl)) * Dd + d0 + dc;
    const bf16x8 f0 = *(const bf16x8*)src;
    const bf16x8 f1 = *(const bf16x8*)(src + 8);
#pragma unroll
    for (int j = 0; j < 8; ++j) { ws0[dc + j][sl] = (float)f0[j]; ws0[dc + 8 + j][sl] = (float)f1[j]; }
  }
  if (t < 128) sm[t >> 1][t & 1] = stats[(size_t)(b * Ss + s0 + (t >> 1)) * 2 + (t & 1)];
  __syncthreads();
  const int dl = t >> 2, sc = (t & 3) * 16;
  const float g = gamma[d0 + dl], be = beta[d0 + dl];
  float* dst = out + ((size_t)(b * Dd + d0 + dl)) * Ss + s0 + sc;
#pragma unroll
  for (int q = 0; q < 4; ++q) {
    float4 o;
    o.x = (ws0[dl][sc + q * 4 + 0] - sm[sc + q * 4 + 0][0]) * sm[sc + q * 4 + 0][1] * g + be;
    o.y = (ws0[dl][sc + q * 4 + 1] - sm[sc + q * 4 + 1][0]) * sm[sc + q * 4 + 1][1] * g + be;
    o.z = (ws0[dl][sc + q * 4 + 2] - sm[sc + q * 4 + 2][0]) * sm[sc + q * 4 + 2][1] * g + be;
    o.w = (ws0[dl][sc + q * 4 + 3] - sm[sc + q * 4 + 3][0]) * sm[sc + q * 4 + 3][1] * g + be;
    *(float4*)(dst + q * 4) = o;
  }
}

extern "C" void kernel_launch(void* const* d_in, const int* in_sizes, int n_in,
                              void* d_out, int out_size, void* d_ws, size_t ws_size,
                              hipStream_t stream) {
  const float* inp   = (const float*)d_in[0];
  const float* Wq    = (const float*)d_in[1];
  const float* bq    = (const float*)d_in[2];
  const float* Wk    = (const float*)d_in[3];
  const float* bk    = (const float*)d_in[4];
  const float* Wv    = (const float*)d_in[5];
  const float* bv    = (const float*)d_in[6];
  const float* Wo    = (const float*)d_in[7];
  const float* bo    = (const float*)d_in[8];
  const float* gamma = (const float*)d_in[9];
  const float* beta  = (const float*)d_in[10];

  char* ws = (char*)d_ws;
  const size_t MB = 1ull << 20;
  __bf16* xb  = (__bf16*)(ws);             // 8 MB   (B,S,D) bf16 (GEMM A + residual source)
  __bf16* Wqt = (__bf16*)(ws + 8 * MB);    // 2 MB each, [n][k] bf16
  __bf16* Wkt = (__bf16*)(ws + 10 * MB);
  __bf16* Wvt = (__bf16*)(ws + 12 * MB);
  __bf16* Wot = (__bf16*)(ws + 14 * MB);
  __bf16* Qb  = (__bf16*)(ws + 16 * MB);   // 8 MB, (B,H,S,64)
  __bf16* Kb  = (__bf16*)(ws + 24 * MB);   // 8 MB, (B,H,S,64)
  __bf16* Vtb = (__bf16*)(ws + 32 * MB);   // 8 MB, (B,H,64,S)  V^T
  __bf16* Ob  = (__bf16*)(ws + 40 * MB);   // 8 MB (B,S,U)
  __bf16* Wb  = (__bf16*)(ws + 16 * MB);   // 8 MB bf16, aliases dead Qb
  float*  partials = (float*)(ws + 8 * MB);            // 512 KB (dead Wqt head)
  float*  stats    = (float*)(ws + 8 * MB + 512 * 1024);

  k_xpose_x<<<dim3(32, 16, 2), 256, 0, stream>>>(inp, xb);
  k_xpose_w<<<dim3(16, 16, 4), 256, 0, stream>>>(Wq, Wk, Wv, Wo, Wqt, Wkt, Wvt, Wot);
  k_gemm_qkv8<<<dim3(192), 512, 0, stream>>>(xb, Wqt, Wkt, Wvt, bq, bk, bv, Qb, Kb, Vtb);
  k_attn6<<<dim3(512), 256, 0, stream>>>(Qb, Kb, Vtb, Ob);
  k_gemm_o<<<dim3(256), 256, 0, stream>>>(Ob, Wot, bo, xb, Wb, partials);
  k_ln_stats<<<dim3(16), 256, 0, stream>>>(partials, stats);
  k_ln_write<<<dim3(16, 32, 2), 256, 0, stream>>>(Wb, stats, gamma, beta, (float*)d_out);
}